// Round 5
// baseline (719.584 us; speedup 1.0000x reference)
//
#include <hip/hip_runtime.h>

typedef __bf16 bf16x8 __attribute__((ext_vector_type(8)));
typedef __bf16 bf16x4 __attribute__((ext_vector_type(4)));
typedef __bf16 bf16x2 __attribute__((ext_vector_type(2)));
typedef float  f32x16 __attribute__((ext_vector_type(16)));
typedef unsigned int u32x4 __attribute__((ext_vector_type(4)));

#define NB   2
#define SEQ  2048
#define NHQ  32
#define NHKV 8
#define HD   128
#define KVSTR (NHKV * HD)          // 1024 floats between consecutive kv rows
#define TSTEP (64 * KVSTR)         // floats between consecutive kv tiles
#define SCL2E 0.12753599963140488f // (1/sqrt(128)) * log2(e)

static __device__ inline unsigned pk2(float a, float b) {
    bf16x2 t = {(__bf16)a, (__bf16)b};
    return __builtin_bit_cast(unsigned, t);
}

__global__ __launch_bounds__(512, 4) void gqa_attn_fwd(
    const float* __restrict__ qg, const float* __restrict__ kg,
    const float* __restrict__ vg, float* __restrict__ og)
{
    // 64 KB shared: K dbuf (32 KB) + V dbuf (32 KB); whole buffer reused as
    // the pair-merge exchange area after the main loop.
    __shared__ __align__(16) char smem[65536];
    __bf16 (*Kl)[8192] = (__bf16(*)[8192])smem;            // [buf][64kv*128d] swz ^(row&15)<<3
    __bf16 (*Vt)[8192] = (__bf16(*)[8192])(smem + 32768);  // [buf][128d*64kv] swz ^((d>>2)&7)<<3

    const int tid  = threadIdx.x;
    const int w    = tid >> 6;
    const int lane = tid & 63;
    const int l31  = lane & 31;
    const int hi   = lane >> 5;
    const int qgrp = w >> 1;          // 0..3 : q sub-group (32 rows)
    const int kvh  = w & 1;           // tile parity this wave computes

    // 1024 blocks, long (high qt) first; backfill balances
    const int bid = blockIdx.x;
    const int qt  = 15 - (bid >> 6);         // 0..15, q-tile of 128 rows
    const int sub = bid & 63;
    const int hq  = sub & 31;
    const int b   = sub >> 5;
    const int qb  = qt * 128;
    const int hkv = hq >> 2;

    const float* kbase = kg + ((size_t)b * SEQ * NHKV + hkv) * HD;
    const float* vbase = vg + ((size_t)b * SEQ * NHKV + hkv) * HD;
    const int ntiles = 2 * qt + 2;
    const int t_max  = 2 * qt + (qgrp >> 1); // this wave's group's last (diagonal) tile

    // ---- Q fragments: lane owns q-row qb+32*qgrp+l31; B-frag k = 8*hi + j --
    const int qrow = qb + qgrp * 32 + l31;
    const float* qp = qg + (((size_t)b * SEQ + qrow) * NHQ + hq) * HD;
    bf16x8 bq[8];
#pragma unroll
    for (int s = 0; s < 8; ++s) {
        const int d0 = s * 16 + hi * 8;
        const float4 f0 = *(const float4*)(qp + d0);
        const float4 f1 = *(const float4*)(qp + d0 + 4);
        bf16x8 t = {(__bf16)f0.x, (__bf16)f0.y, (__bf16)f0.z, (__bf16)f0.w,
                    (__bf16)f1.x, (__bf16)f1.y, (__bf16)f1.z, (__bf16)f1.w};
        bq[s] = t;
    }

    // ---- staging: running pointers + per-thread constant offsets -----------
    const int krow0 = tid >> 5;            // 0..15
    const int kdq   = (tid & 31) * 4;      // 0..124
    const float* kp = kbase + (size_t)krow0 * KVSTR + kdq;
    const float* vp = vbase + (size_t)krow0 * 4 * KVSTR + kdq;
    const int kout = krow0 * 128 + (kdq ^ (krow0 << 3));
    const int vout = (4 * (tid & 31)) * 64 + ((krow0 * 4) ^ ((tid & 7) << 3));

    auto loadK = [&](float4 kr[4]) {
#pragma unroll
        for (int i = 0; i < 4; ++i) kr[i] = *(const float4*)(kp + i * 16 * KVSTR);
        kp += TSTEP;
    };
    auto loadV = [&](float4 vr[4]) {
#pragma unroll
        for (int j = 0; j < 4; ++j) vr[j] = *(const float4*)(vp + j * KVSTR);
        vp += TSTEP;
    };
    auto storeK = [&](int buf, const float4 kr[4]) {
#pragma unroll
        for (int i = 0; i < 4; ++i) {
            bf16x4 kb4 = {(__bf16)kr[i].x, (__bf16)kr[i].y, (__bf16)kr[i].z, (__bf16)kr[i].w};
            *(bf16x4*)&Kl[buf][kout + i * 2048] = kb4;
        }
    };
    auto storeV = [&](int buf, const float4 vr[4]) {
#pragma unroll
        for (int c = 0; c < 4; ++c) {
            const float x0 = (c == 0) ? vr[0].x : (c == 1) ? vr[0].y : (c == 2) ? vr[0].z : vr[0].w;
            const float x1 = (c == 0) ? vr[1].x : (c == 1) ? vr[1].y : (c == 2) ? vr[1].z : vr[1].w;
            const float x2 = (c == 0) ? vr[2].x : (c == 1) ? vr[2].y : (c == 2) ? vr[2].z : vr[2].w;
            const float x3 = (c == 0) ? vr[3].x : (c == 1) ? vr[3].y : (c == 2) ? vr[3].z : vr[3].w;
            bf16x4 o = {(__bf16)x0, (__bf16)x1, (__bf16)x2, (__bf16)x3};
            *(bf16x4*)&Vt[buf][vout + c * 64] = o;
        }
    };

    f32x16 acc[4] = {};       // acc[db]: O[q=crow(r,hi)][d=db*32+l31] (partial, this parity)
    float m_r = -1e30f, l_r = 0.f;   // scaled-log2 domain

    // ---- prologue: tile 0 -> LDS buf0; tile 1 -> regs ----------------------
    float4 kr[4], vr[4];
    loadK(kr); loadV(vr);
    storeK(0, kr); storeV(0, vr);
    if (ntiles > 1) { loadK(kr); loadV(vr); }

    const int swk = (l31 & 15) << 3;   // K read swizzle (lane-constant)
    const int swv = (l31 >> 2) << 3;   // V read swizzle (lane-constant)

    for (int t = 0; t < ntiles; ++t) {
        const int cur = t & 1;
        __syncthreads();      // prev iter reads of alt-buffers complete

        if (t + 1 < ntiles) { storeK(cur ^ 1, kr); storeV(cur ^ 1, vr); }
        if (t + 2 < ntiles) { loadK(kr); loadV(vr); }

        const bool active = ((t & 1) == kvh) && (t <= t_max);
        if (active) {
            // ---- swapped QK^T: S^T[kv][q], A=K, B=Q ------------------------
            f32x16 sf[2];
            __builtin_amdgcn_s_setprio(1);
#pragma unroll
            for (int kb = 0; kb < 2; ++kb) {
                sf[kb] = (f32x16)(0.f);
                const int krow = kb * 32 + l31;
#pragma unroll
                for (int s = 0; s < 8; ++s) {
                    const int d0 = s * 16 + hi * 8;
                    const bf16x8 ak = *(const bf16x8*)&Kl[cur][krow * 128 + (d0 ^ swk)];
                    sf[kb] = __builtin_amdgcn_mfma_f32_32x32x16_bf16(ak, bq[s], sf[kb], 0, 0, 0);
                }
            }
            __builtin_amdgcn_s_setprio(0);

            // ---- causal mask on the diagonal tile --------------------------
            if (t == t_max) {
#pragma unroll
                for (int kb = 0; kb < 2; ++kb)
#pragma unroll
                    for (int r = 0; r < 16; ++r) {
                        const int kvg = t * 64 + kb * 32 + ((r & 3) + ((r >> 2) << 3) + (hi << 2));
                        if (kvg > qrow) sf[kb][r] = -1e30f;
                    }
            }
            // ---- row max tree + cross-half ---------------------------------
            float t16[16];
#pragma unroll
            for (int r = 0; r < 16; ++r) t16[r] = fmaxf(sf[0][r], sf[1][r]);
#pragma unroll
            for (int r = 0; r < 8; ++r) t16[r] = fmaxf(t16[r], t16[r + 8]);
#pragma unroll
            for (int r = 0; r < 4; ++r) t16[r] = fmaxf(t16[r], t16[r + 4]);
            float pm = fmaxf(fmaxf(t16[0], t16[1]), fmaxf(t16[2], t16[3]));
            pm = fmaxf(pm, __shfl_xor(pm, 32));
            const float pms = pm * SCL2E;

            if (__any(pms - m_r > 8.0f)) {            // T13 defer-rescale
                const float mn = fmaxf(m_r, pms);
                const float alpha = exp2f(m_r - mn);
                m_r = mn;
                l_r *= alpha;
#pragma unroll
                for (int r = 0; r < 16; ++r) {
                    const float ab = __shfl(alpha, (r & 3) + ((r >> 2) << 3) + (hi << 2));
#pragma unroll
                    for (int db = 0; db < 4; ++db) acc[db][r] *= ab;
                }
            }

            // ---- exp (scale folded) + row sum ------------------------------
            float p[2][16];
#pragma unroll
            for (int kb = 0; kb < 2; ++kb)
#pragma unroll
                for (int r = 0; r < 16; ++r)
                    p[kb][r] = exp2f(fmaf(sf[kb][r], SCL2E, -m_r));
            {
                float s16[16];
#pragma unroll
                for (int r = 0; r < 16; ++r) s16[r] = p[0][r] + p[1][r];
#pragma unroll
                for (int r = 0; r < 8; ++r) s16[r] += s16[r + 8];
#pragma unroll
                for (int r = 0; r < 4; ++r) s16[r] += s16[r + 4];
                float rs = (s16[0] + s16[1]) + (s16[2] + s16[3]);
                rs += __shfl_xor(rs, 32);
                l_r += rs;
            }

            // ---- T12: P -> bf16 A-frags via pack + permlane32_swap ---------
            bf16x8 pa[4];
#pragma unroll
            for (int ks = 0; ks < 4; ++ks) {
                const int kb = ks >> 1, c = (ks & 1) * 8;
                unsigned x0 = pk2(p[kb][c + 0], p[kb][c + 1]);
                unsigned x1 = pk2(p[kb][c + 2], p[kb][c + 3]);
                unsigned y0 = pk2(p[kb][c + 4], p[kb][c + 5]);
                unsigned y1 = pk2(p[kb][c + 6], p[kb][c + 7]);
                asm volatile("v_permlane32_swap_b32 %0, %1" : "+v"(x0), "+v"(y0));
                asm volatile("v_permlane32_swap_b32 %0, %1" : "+v"(x1), "+v"(y1));
                u32x4 u = {x0, x1, y0, y1};
                pa[ks] = __builtin_bit_cast(bf16x8, u);
            }

            // ---- PV: acc[db] += P(32q x 16kv) * V(16kv x 32d) --------------
            __builtin_amdgcn_s_setprio(1);
#pragma unroll
            for (int db = 0; db < 4; ++db) {
                const int dbase = (db * 32 + l31) * 64;
#pragma unroll
                for (int ks = 0; ks < 4; ++ks) {
                    const int kvo = ks * 16 + hi * 8;
                    const bf16x8 bv = *(const bf16x8*)&Vt[cur][dbase + (kvo ^ swv)];
                    acc[db] = __builtin_amdgcn_mfma_f32_32x32x16_bf16(pa[ks], bv, acc[db], 0, 0, 0);
                }
            }
            __builtin_amdgcn_s_setprio(0);
        }
    }

    // ---- pair merge: waves (2g, 2g+1) combine flash states -----------------
    __syncthreads();                       // LDS reusable from here
    float* MS = (float*)smem;              // [8][32] row maxes
    float* LS = MS + 256;                  // [8][32] row sums
    if (!hi) { MS[w * 32 + l31] = m_r; LS[w * 32 + l31] = l_r; }
    __syncthreads();
    float fA = 0.f, fB = 0.f;
    if (!kvh) {
        const float mB = MS[(w + 1) * 32 + l31];
        const float lB = LS[(w + 1) * 32 + l31];
        const float mm = fmaxf(m_r, mB);
        const float aA = exp2f(m_r - mm);
        const float aB = exp2f(mB - mm);
        const float li = 1.0f / (aA * l_r + aB * lB);
        fA = aA * li; fB = aB * li;
    }
    __syncthreads();                       // m/l reads done before acc overwrite
    float* XA = (float*)smem;              // [idx 64][pair 4][lane 64] = 64 KB
    if (kvh) {
#pragma unroll
        for (int db = 0; db < 4; ++db)
#pragma unroll
            for (int r = 0; r < 16; ++r)
                XA[(db * 16 + r) * 256 + qgrp * 64 + lane] = acc[db][r];
    }
    __syncthreads();
    if (!kvh) {
#pragma unroll
        for (int r = 0; r < 16; ++r) {
            const int crow = (r & 3) + ((r >> 2) << 3) + (hi << 2);
            const float gA = __shfl(fA, crow);
            const float gB = __shfl(fB, crow);
            const int qg_row = qb + qgrp * 32 + crow;
            float* op = og + (((size_t)b * SEQ + qg_row) * NHQ + hq) * HD + l31;
#pragma unroll
            for (int db = 0; db < 4; ++db) {
                const float ob = XA[(db * 16 + r) * 256 + qgrp * 64 + lane];
                op[db * 32] = fmaf(gA, acc[db][r], gB * ob);
            }
        }
    }
}

extern "C" void kernel_launch(void* const* d_in, const int* in_sizes, int n_in,
                              void* d_out, int out_size, void* d_ws, size_t ws_size,
                              hipStream_t stream) {
    const float* q = (const float*)d_in[0];
    const float* k = (const float*)d_in[1];
    const float* v = (const float*)d_in[2];
    float* out = (float*)d_out;
    dim3 grid((SEQ / 128) * NHQ * NB);   // 1024 blocks, long-first + backfill
    dim3 block(512);
    gqa_attn_fwd<<<grid, block, 0, stream>>>(q, k, v, out);
}

// Round 6
// 210.417 us; speedup vs baseline: 3.4198x; 3.4198x over previous
//
#include <hip/hip_runtime.h>

typedef __bf16 bf16x8 __attribute__((ext_vector_type(8)));
typedef __bf16 bf16x4 __attribute__((ext_vector_type(4)));
typedef __bf16 bf16x2 __attribute__((ext_vector_type(2)));
typedef float  f32x16 __attribute__((ext_vector_type(16)));
typedef unsigned int u32x4 __attribute__((ext_vector_type(4)));

#define NB   2
#define SEQ  2048
#define NHQ  32
#define NHKV 8
#define HD   128
#define KVSTR (NHKV * HD)          // 1024 floats between consecutive kv rows
#define TSTEP (64 * KVSTR)         // floats between consecutive kv tiles
#define SCL2E 0.12753599963140488f // (1/sqrt(128)) * log2(e)

static __device__ inline unsigned pk2(float a, float b) {
    bf16x2 t = {(__bf16)a, (__bf16)b};
    return __builtin_bit_cast(unsigned, t);
}

__global__ __launch_bounds__(512, 2) void gqa_attn_fwd(
    const float* __restrict__ qg, const float* __restrict__ kg,
    const float* __restrict__ vg, float* __restrict__ og)
{
    // 64 KB shared: K dbuf (32 KB) + V dbuf (32 KB); reused as the
    // pair-merge exchange area after each item's main loop.
    __shared__ __align__(16) char smem[65536];
    __bf16 (*Kl)[8192] = (__bf16(*)[8192])smem;            // [buf][64kv*128d] swz ^(row&15)<<3
    __bf16 (*Vt)[8192] = (__bf16(*)[8192])(smem + 32768);  // [buf][128d*64kv] swz ^((d>>2)&7)<<3

    const int tid  = threadIdx.x;
    const int w    = tid >> 6;
    const int lane = tid & 63;
    const int l31  = lane & 31;
    const int hi   = lane >> 5;
    const int qgrp = w >> 1;          // 0..3 : q sub-group (32 rows)
    const int kvh  = w & 1;           // tile parity this wave computes

    // 512 persistent blocks; each runs two complementary 128-row q-tiles
    // (qtA in 8..15, qtB = 15-qtA) => exactly 34 staged KV tiles per block.
    const int bid = blockIdx.x;
    const int qtA = 8 + (bid >> 6);
    const int sub = bid & 63;
    const int hq  = sub & 31;
    const int b   = sub >> 5;
    const int hkv = hq >> 2;

    const float* kbase = kg + ((size_t)b * SEQ * NHKV + hkv) * HD;
    const float* vbase = vg + ((size_t)b * SEQ * NHKV + hkv) * HD;

    // per-thread constant staging offsets
    const int krow0 = tid >> 5;            // 0..15
    const int kdq   = (tid & 31) * 4;      // 0..124
    const int kout  = krow0 * 128 + (kdq ^ (krow0 << 3));
    const int vout  = (4 * (tid & 31)) * 64 + ((krow0 * 4) ^ ((tid & 7) << 3));
    const int swk   = (l31 & 15) << 3;     // K read swizzle (lane-constant)
    const int swv   = (l31 >> 2) << 3;     // V read swizzle (lane-constant)

    const float* kp;
    const float* vp;
    auto loadK = [&](float4 kr[4]) {
#pragma unroll
        for (int i = 0; i < 4; ++i) kr[i] = *(const float4*)(kp + i * 16 * KVSTR);
        kp += TSTEP;
    };
    auto loadV = [&](float4 vr[4]) {
#pragma unroll
        for (int j = 0; j < 4; ++j) vr[j] = *(const float4*)(vp + j * KVSTR);
        vp += TSTEP;
    };
    auto storeK = [&](int buf, const float4 kr[4]) {
#pragma unroll
        for (int i = 0; i < 4; ++i) {
            bf16x4 kb4 = {(__bf16)kr[i].x, (__bf16)kr[i].y, (__bf16)kr[i].z, (__bf16)kr[i].w};
            *(bf16x4*)&Kl[buf][kout + i * 2048] = kb4;
        }
    };
    auto storeV = [&](int buf, const float4 vr[4]) {
#pragma unroll
        for (int c = 0; c < 4; ++c) {
            const float x0 = (c == 0) ? vr[0].x : (c == 1) ? vr[0].y : (c == 2) ? vr[0].z : vr[0].w;
            const float x1 = (c == 0) ? vr[1].x : (c == 1) ? vr[1].y : (c == 2) ? vr[1].z : vr[1].w;
            const float x2 = (c == 0) ? vr[2].x : (c == 1) ? vr[2].y : (c == 2) ? vr[2].z : vr[2].w;
            const float x3 = (c == 0) ? vr[3].x : (c == 1) ? vr[3].y : (c == 2) ? vr[3].z : vr[3].w;
            bf16x4 o = {(__bf16)x0, (__bf16)x1, (__bf16)x2, (__bf16)x3};
            *(bf16x4*)&Vt[buf][vout + c * 64] = o;
        }
    };

    for (int it = 0; it < 2; ++it) {
        const int qt = (it == 0) ? qtA : (15 - qtA);
        const int qb = qt * 128;
        const int ntiles = 2 * qt + 2;
        const int t_max  = 2 * qt + (qgrp >> 1);   // this wave's diagonal tile

        // ---- Q fragments: lane owns q-row qb+32*qgrp+l31; B-frag k=8*hi+j --
        const int qrow = qb + qgrp * 32 + l31;
        const float* qp = qg + (((size_t)b * SEQ + qrow) * NHQ + hq) * HD;
        bf16x8 bq[8];
#pragma unroll
        for (int s = 0; s < 8; ++s) {
            const int d0 = s * 16 + hi * 8;
            const float4 f0 = *(const float4*)(qp + d0);
            const float4 f1 = *(const float4*)(qp + d0 + 4);
            bf16x8 t = {(__bf16)f0.x, (__bf16)f0.y, (__bf16)f0.z, (__bf16)f0.w,
                        (__bf16)f1.x, (__bf16)f1.y, (__bf16)f1.z, (__bf16)f1.w};
            bq[s] = t;
        }

        kp = kbase + (size_t)krow0 * KVSTR + kdq;
        vp = vbase + (size_t)krow0 * 4 * KVSTR + kdq;

        f32x16 acc[4] = {};            // O[q=crow(r,hi)][d=db*32+l31] (this parity)
        float m_r = -1e30f, l_r = 0.f; // scaled-log2 domain

        // ---- prologue: tile 0 -> LDS buf0; tile 1 -> regs ------------------
        float4 kr[4], vr[4];
        loadK(kr); loadV(vr);
        __syncthreads();               // prev item's LDS use fully done
        storeK(0, kr); storeV(0, vr);
        loadK(kr); loadV(vr);          // ntiles >= 2 always

        for (int t = 0; t < ntiles; ++t) {
            const int cur = t & 1;
            __syncthreads();           // prev iter reads of alt-buffers done

            if (t + 1 < ntiles) { storeK(cur ^ 1, kr); storeV(cur ^ 1, vr); }
            if (t + 2 < ntiles) { loadK(kr); loadV(vr); }

            const bool active = ((t & 1) == kvh) && (t <= t_max);
            if (active) {
                // ---- swapped QK^T: S^T[kv][q], A=K, B=Q --------------------
                f32x16 sf[2];
                __builtin_amdgcn_s_setprio(1);
#pragma unroll
                for (int kb = 0; kb < 2; ++kb) {
                    sf[kb] = (f32x16)(0.f);
                    const int krow = kb * 32 + l31;
#pragma unroll
                    for (int s = 0; s < 8; ++s) {
                        const int d0 = s * 16 + hi * 8;
                        const bf16x8 ak = *(const bf16x8*)&Kl[cur][krow * 128 + (d0 ^ swk)];
                        sf[kb] = __builtin_amdgcn_mfma_f32_32x32x16_bf16(ak, bq[s], sf[kb], 0, 0, 0);
                    }
                }
                __builtin_amdgcn_s_setprio(0);

                // ---- causal mask on the diagonal tile ----------------------
                if (t == t_max) {
#pragma unroll
                    for (int kb = 0; kb < 2; ++kb)
#pragma unroll
                        for (int r = 0; r < 16; ++r) {
                            const int kvg = t * 64 + kb * 32 + ((r & 3) + ((r >> 2) << 3) + (hi << 2));
                            if (kvg > qrow) sf[kb][r] = -1e30f;
                        }
                }
                // ---- row max tree + cross-half -----------------------------
                float t16[16];
#pragma unroll
                for (int r = 0; r < 16; ++r) t16[r] = fmaxf(sf[0][r], sf[1][r]);
#pragma unroll
                for (int r = 0; r < 8; ++r) t16[r] = fmaxf(t16[r], t16[r + 8]);
#pragma unroll
                for (int r = 0; r < 4; ++r) t16[r] = fmaxf(t16[r], t16[r + 4]);
                float pm = fmaxf(fmaxf(t16[0], t16[1]), fmaxf(t16[2], t16[3]));
                pm = fmaxf(pm, __shfl_xor(pm, 32));
                const float pms = pm * SCL2E;

                if (__any(pms - m_r > 8.0f)) {        // T13 defer-rescale
                    const float mn = fmaxf(m_r, pms);
                    const float alpha = exp2f(m_r - mn);
                    m_r = mn;
                    l_r *= alpha;
#pragma unroll
                    for (int r = 0; r < 16; ++r) {
                        const float ab = __shfl(alpha, (r & 3) + ((r >> 2) << 3) + (hi << 2));
#pragma unroll
                        for (int db = 0; db < 4; ++db) acc[db][r] *= ab;
                    }
                }

                // ---- exp (scale folded) + row sum --------------------------
                float p[2][16];
#pragma unroll
                for (int kb = 0; kb < 2; ++kb)
#pragma unroll
                    for (int r = 0; r < 16; ++r)
                        p[kb][r] = exp2f(fmaf(sf[kb][r], SCL2E, -m_r));
                {
                    float s16[16];
#pragma unroll
                    for (int r = 0; r < 16; ++r) s16[r] = p[0][r] + p[1][r];
#pragma unroll
                    for (int r = 0; r < 8; ++r) s16[r] += s16[r + 8];
#pragma unroll
                    for (int r = 0; r < 4; ++r) s16[r] += s16[r + 4];
                    float rs = (s16[0] + s16[1]) + (s16[2] + s16[3]);
                    rs += __shfl_xor(rs, 32);
                    l_r += rs;
                }

                // ---- T12: P -> bf16 A-frags via pack + permlane32_swap -----
                bf16x8 pa[4];
#pragma unroll
                for (int ks = 0; ks < 4; ++ks) {
                    const int kb = ks >> 1, c = (ks & 1) * 8;
                    unsigned x0 = pk2(p[kb][c + 0], p[kb][c + 1]);
                    unsigned x1 = pk2(p[kb][c + 2], p[kb][c + 3]);
                    unsigned y0 = pk2(p[kb][c + 4], p[kb][c + 5]);
                    unsigned y1 = pk2(p[kb][c + 6], p[kb][c + 7]);
                    asm volatile("v_permlane32_swap_b32 %0, %1" : "+v"(x0), "+v"(y0));
                    asm volatile("v_permlane32_swap_b32 %0, %1" : "+v"(x1), "+v"(y1));
                    u32x4 u = {x0, x1, y0, y1};
                    pa[ks] = __builtin_bit_cast(bf16x8, u);
                }

                // ---- PV: acc[db] += P(32q x 16kv) * V(16kv x 32d) ----------
                __builtin_amdgcn_s_setprio(1);
#pragma unroll
                for (int db = 0; db < 4; ++db) {
                    const int dbase = (db * 32 + l31) * 64;
#pragma unroll
                    for (int ks = 0; ks < 4; ++ks) {
                        const int kvo = ks * 16 + hi * 8;
                        const bf16x8 bv = *(const bf16x8*)&Vt[cur][dbase + (kvo ^ swv)];
                        acc[db] = __builtin_amdgcn_mfma_f32_32x32x16_bf16(pa[ks], bv, acc[db], 0, 0, 0);
                    }
                }
                __builtin_amdgcn_s_setprio(0);
            }
        }

        // ---- pair merge: waves (2g, 2g+1) combine flash states -------------
        __syncthreads();                   // LDS reusable from here
        float* MS = (float*)smem;          // [8][32] row maxes
        float* LS = MS + 256;              // [8][32] row sums
        if (!hi) { MS[w * 32 + l31] = m_r; LS[w * 32 + l31] = l_r; }
        __syncthreads();
        float fA = 0.f, fB = 0.f;
        if (!kvh) {
            const float mB = MS[(w + 1) * 32 + l31];
            const float lB = LS[(w + 1) * 32 + l31];
            const float mm = fmaxf(m_r, mB);
            const float aA = exp2f(m_r - mm);
            const float aB = exp2f(mB - mm);
            const float li = 1.0f / (aA * l_r + aB * lB);
            fA = aA * li; fB = aB * li;
        }
        __syncthreads();                   // m/l reads done before acc overwrite
        float* XA = (float*)smem;          // [idx 64][pair 4][lane 64] = 64 KB
        if (kvh) {
#pragma unroll
            for (int db = 0; db < 4; ++db)
#pragma unroll
                for (int r = 0; r < 16; ++r)
                    XA[(db * 16 + r) * 256 + qgrp * 64 + lane] = acc[db][r];
        }
        __syncthreads();
        if (!kvh) {
#pragma unroll
            for (int r = 0; r < 16; ++r) {
                const int crow = (r & 3) + ((r >> 2) << 3) + (hi << 2);
                const float gA = __shfl(fA, crow);
                const float gB = __shfl(fB, crow);
                const int qg_row = qb + qgrp * 32 + crow;
                float* op = og + (((size_t)b * SEQ + qg_row) * NHQ + hq) * HD + l31;
#pragma unroll
                for (int db = 0; db < 4; ++db) {
                    const float ob = XA[(db * 16 + r) * 256 + qgrp * 64 + lane];
                    op[db * 32] = fmaf(gA, acc[db][r], gB * ob);
                }
            }
        }
    }
}

extern "C" void kernel_launch(void* const* d_in, const int* in_sizes, int n_in,
                              void* d_out, int out_size, void* d_ws, size_t ws_size,
                              hipStream_t stream) {
    const float* q = (const float*)d_in[0];
    const float* k = (const float*)d_in[1];
    const float* v = (const float*)d_in[2];
    float* out = (float*)d_out;
    dim3 grid(512);                  // 2 blocks/CU, uniform 34 tiles each
    dim3 block(512);
    gqa_attn_fwd<<<grid, block, 0, stream>>>(q, k, v, out);
}

// Round 7
// 156.691 us; speedup vs baseline: 4.5924x; 1.3429x over previous
//
#include <hip/hip_runtime.h>

typedef __bf16 bf16x8 __attribute__((ext_vector_type(8)));
typedef __bf16 bf16x4 __attribute__((ext_vector_type(4)));
typedef __bf16 bf16x2 __attribute__((ext_vector_type(2)));
typedef float  f32x16 __attribute__((ext_vector_type(16)));
typedef unsigned int u32x4 __attribute__((ext_vector_type(4)));

#define NB   2
#define SEQ  2048
#define NHQ  32
#define NHKV 8
#define HD   128
#define KVSTR (NHKV * HD)          // 1024 floats between consecutive kv rows
#define TSTEP (64 * KVSTR)         // floats between consecutive kv tiles
#define SCL2E 0.12753599963140488f // (1/sqrt(128)) * log2(e)

static __device__ inline unsigned pk2(float a, float b) {
    bf16x2 t = {(__bf16)a, (__bf16)b};
    return __builtin_bit_cast(unsigned, t);
}

__global__ __launch_bounds__(512, 2) void gqa_attn_fwd(
    const float* __restrict__ qg, const float* __restrict__ kg,
    const float* __restrict__ vg, float* __restrict__ og)
{
    // K: 2 x [64 kv][128 d] bf16, swz elem ^= (row&15)<<3           32 KB
    // V: 2 x [128 d][64 kv] bf16, swz elem ^= ((d>>2)&7)<<3         32 KB
    __shared__ __align__(16) __bf16 Kl[2][64 * 128];
    __shared__ __align__(16) __bf16 Vt[2][128 * 64];

    const int tid  = threadIdx.x;
    const int w    = tid >> 6;
    const int lane = tid & 63;
    const int l31  = lane & 31;
    const int hi   = lane >> 5;

    // CONSECUTIVE bids are complementary: pair (2i, 2i+1) -> qt (7-x, x),
    // so any CU holding adjacent blocks has a uniform 36-tile total.
    const int bid = blockIdx.x;
    const int i2  = bid >> 1;
    const int x   = i2 >> 6;                 // 0..3
    const int qt  = (bid & 1) ? x : (7 - x); // sums to 7 per consecutive pair
    const int sub = i2 & 63;
    const int hq  = sub & 31;
    const int b   = sub >> 5;
    const int qb  = qt * 256;
    const int hkv = hq >> 2;

    const float* kbase = kg + ((size_t)b * SEQ * NHKV + hkv) * HD;
    const float* vbase = vg + ((size_t)b * SEQ * NHKV + hkv) * HD;
    const int ntiles = qt * 4 + 4;
    const int Tw     = qt * 4 + (w >> 1) + 1;    // this wave's active tiles

    // ---- Q fragments: lane owns q-row qb+32w+l31; B-frag k = 8*hi + j ------
    const int qrow = qb + w * 32 + l31;
    const float* qp = qg + (((size_t)b * SEQ + qrow) * NHQ + hq) * HD;
    bf16x8 bq[8];
#pragma unroll
    for (int s = 0; s < 8; ++s) {
        const int d0 = s * 16 + hi * 8;
        const float4 f0 = *(const float4*)(qp + d0);
        const float4 f1 = *(const float4*)(qp + d0 + 4);
        bf16x8 t = {(__bf16)f0.x, (__bf16)f0.y, (__bf16)f0.z, (__bf16)f0.w,
                    (__bf16)f1.x, (__bf16)f1.y, (__bf16)f1.z, (__bf16)f1.w};
        bq[s] = t;
    }

    // ---- staging: running pointers + per-thread constant offsets -----------
    const int krow0 = tid >> 5;            // 0..15
    const int kdq   = (tid & 31) * 4;      // 0..124
    const float* kp = kbase + (size_t)krow0 * KVSTR + kdq;
    const float* vp = vbase + (size_t)krow0 * 4 * KVSTR + kdq;
    const int kout = krow0 * 128 + (kdq ^ (krow0 << 3));
    const int vout = (4 * (tid & 31)) * 64 + ((krow0 * 4) ^ ((tid & 7) << 3));

    auto loadK = [&](float4 kr[4]) {
#pragma unroll
        for (int i = 0; i < 4; ++i) kr[i] = *(const float4*)(kp + i * 16 * KVSTR);
        kp += TSTEP;
    };
    auto loadV = [&](float4 vr[4]) {
#pragma unroll
        for (int j = 0; j < 4; ++j) vr[j] = *(const float4*)(vp + j * KVSTR);
        vp += TSTEP;
    };
    auto storeK = [&](int buf, const float4 kr[4]) {
#pragma unroll
        for (int i = 0; i < 4; ++i) {
            bf16x4 kb4 = {(__bf16)kr[i].x, (__bf16)kr[i].y, (__bf16)kr[i].z, (__bf16)kr[i].w};
            *(bf16x4*)&Kl[buf][kout + i * 2048] = kb4;
        }
    };
    auto storeV = [&](int buf, const float4 vr[4]) {
#pragma unroll
        for (int c = 0; c < 4; ++c) {
            const float x0 = (c == 0) ? vr[0].x : (c == 1) ? vr[0].y : (c == 2) ? vr[0].z : vr[0].w;
            const float x1 = (c == 0) ? vr[1].x : (c == 1) ? vr[1].y : (c == 2) ? vr[1].z : vr[1].w;
            const float x2 = (c == 0) ? vr[2].x : (c == 1) ? vr[2].y : (c == 2) ? vr[2].z : vr[2].w;
            const float x3 = (c == 0) ? vr[3].x : (c == 1) ? vr[3].y : (c == 2) ? vr[3].z : vr[3].w;
            bf16x4 o = {(__bf16)x0, (__bf16)x1, (__bf16)x2, (__bf16)x3};
            *(bf16x4*)&Vt[buf][vout + c * 64] = o;
        }
    };

    f32x16 acc[4] = {};       // acc[db]: O[q=crow(r,hi)][d=db*32+l31]
    float m_r = -1e30f, l_r = 0.f;   // scaled-log2 domain

    // ---- prologue: tile 0 -> LDS buf0; tile 1 -> regs ----------------------
    float4 kr[4], vr[4];
    loadK(kr); loadV(vr);
    storeK(0, kr); storeV(0, vr);
    if (ntiles > 1) { loadK(kr); loadV(vr); }

    const int swk = (l31 & 15) << 3;   // K read swizzle (lane-constant)
    const int swv = (l31 >> 2) << 3;   // V read swizzle (lane-constant)

    for (int t = 0; t < ntiles; ++t) {
        const int cur = t & 1;
        __syncthreads();      // prev iter reads of alt-buffers complete

        if (t + 1 < ntiles) { storeK(cur ^ 1, kr); storeV(cur ^ 1, vr); }
        if (t + 2 < ntiles) { loadK(kr); loadV(vr); }

        const bool active = (t < Tw);
        if (active) {
            // ---- swapped QK^T: S^T[kv][q], A=K, B=Q ------------------------
            f32x16 sf[2];
            __builtin_amdgcn_s_setprio(1);
#pragma unroll
            for (int kb = 0; kb < 2; ++kb) {
                sf[kb] = (f32x16)(0.f);
                const int krow = kb * 32 + l31;
#pragma unroll
                for (int s = 0; s < 8; ++s) {
                    const int d0 = s * 16 + hi * 8;
                    const bf16x8 ak = *(const bf16x8*)&Kl[cur][krow * 128 + (d0 ^ swk)];
                    sf[kb] = __builtin_amdgcn_mfma_f32_32x32x16_bf16(ak, bq[s], sf[kb], 0, 0, 0);
                }
            }
            __builtin_amdgcn_s_setprio(0);

            // ---- mask (raw domain), max tree, defer-rescale ----------------
            if (t == Tw - 1) {
#pragma unroll
                for (int kb = 0; kb < 2; ++kb)
#pragma unroll
                    for (int r = 0; r < 16; ++r) {
                        const int kvg = t * 64 + kb * 32 + ((r & 3) + ((r >> 2) << 3) + (hi << 2));
                        if (kvg > qrow) sf[kb][r] = -1e30f;
                    }
            }
            float t16[16];
#pragma unroll
            for (int r = 0; r < 16; ++r) t16[r] = fmaxf(sf[0][r], sf[1][r]);
#pragma unroll
            for (int r = 0; r < 8; ++r) t16[r] = fmaxf(t16[r], t16[r + 8]);
#pragma unroll
            for (int r = 0; r < 4; ++r) t16[r] = fmaxf(t16[r], t16[r + 4]);
            float pm = fmaxf(fmaxf(t16[0], t16[1]), fmaxf(t16[2], t16[3]));
            pm = fmaxf(pm, __shfl_xor(pm, 32));
            const float pms = pm * SCL2E;

            if (__any(pms - m_r > 8.0f)) {            // T13
                const float mn = fmaxf(m_r, pms);
                const float alpha = exp2f(m_r - mn);
                m_r = mn;
                l_r *= alpha;
#pragma unroll
                for (int r = 0; r < 16; ++r) {
                    const float ab = __shfl(alpha, (r & 3) + ((r >> 2) << 3) + (hi << 2));
#pragma unroll
                    for (int db = 0; db < 4; ++db) acc[db][r] *= ab;
                }
            }

            // ---- exp (scale folded into fma) + row sum ---------------------
            float p[2][16];
#pragma unroll
            for (int kb = 0; kb < 2; ++kb)
#pragma unroll
                for (int r = 0; r < 16; ++r)
                    p[kb][r] = exp2f(fmaf(sf[kb][r], SCL2E, -m_r));
            {
                float s16[16];
#pragma unroll
                for (int r = 0; r < 16; ++r) s16[r] = p[0][r] + p[1][r];
#pragma unroll
                for (int r = 0; r < 8; ++r) s16[r] += s16[r + 8];
#pragma unroll
                for (int r = 0; r < 4; ++r) s16[r] += s16[r + 4];
                float rs = (s16[0] + s16[1]) + (s16[2] + s16[3]);
                rs += __shfl_xor(rs, 32);
                l_r += rs;
            }

            // ---- T12: P -> bf16 A-frags via pack + permlane32_swap ---------
            bf16x8 pa[4];
#pragma unroll
            for (int ks = 0; ks < 4; ++ks) {
                const int kb = ks >> 1, c = (ks & 1) * 8;
                unsigned x0 = pk2(p[kb][c + 0], p[kb][c + 1]);
                unsigned x1 = pk2(p[kb][c + 2], p[kb][c + 3]);
                unsigned y0 = pk2(p[kb][c + 4], p[kb][c + 5]);
                unsigned y1 = pk2(p[kb][c + 6], p[kb][c + 7]);
                asm volatile("v_permlane32_swap_b32 %0, %1" : "+v"(x0), "+v"(y0));
                asm volatile("v_permlane32_swap_b32 %0, %1" : "+v"(x1), "+v"(y1));
                u32x4 u = {x0, x1, y0, y1};
                pa[ks] = __builtin_bit_cast(bf16x8, u);
            }

            // ---- PV: acc[db] += P(32q x 16kv) * V(16kv x 32d) --------------
            __builtin_amdgcn_s_setprio(1);
#pragma unroll
            for (int db = 0; db < 4; ++db) {
                const int dbase = (db * 32 + l31) * 64;
#pragma unroll
                for (int ks = 0; ks < 4; ++ks) {
                    const int kvo = ks * 16 + hi * 8;
                    const bf16x8 bv = *(const bf16x8*)&Vt[cur][dbase + (kvo ^ swv)];
                    acc[db] = __builtin_amdgcn_mfma_f32_32x32x16_bf16(pa[ks], bv, acc[db], 0, 0, 0);
                }
            }
            __builtin_amdgcn_s_setprio(0);
        }
    }

    // ---- epilogue: out = acc / l -------------------------------------------
    const float linv = 1.0f / l_r;
#pragma unroll
    for (int r = 0; r < 16; ++r) {
        const int crow = (r & 3) + ((r >> 2) << 3) + (hi << 2);
        const float lb = __shfl(linv, crow);
        const int qg_row = qb + w * 32 + crow;
        float* op = og + (((size_t)b * SEQ + qg_row) * NHQ + hq) * HD + l31;
#pragma unroll
        for (int db = 0; db < 4; ++db) op[db * 32] = acc[db][r] * lb;
    }
}

extern "C" void kernel_launch(void* const* d_in, const int* in_sizes, int n_in,
                              void* d_out, int out_size, void* d_ws, size_t ws_size,
                              hipStream_t stream) {
    const float* q = (const float*)d_in[0];
    const float* k = (const float*)d_in[1];
    const float* v = (const float*)d_in[2];
    float* out = (float*)d_out;
    dim3 grid((SEQ / 256) * NHQ * NB);   // 512 blocks, consecutive-complementary
    dim3 block(512);
    gqa_attn_fwd<<<grid, block, 0, stream>>>(q, k, v, out);
}

// Round 8
// 145.193 us; speedup vs baseline: 4.9560x; 1.0792x over previous
//
#include <hip/hip_runtime.h>

typedef __bf16 bf16x8 __attribute__((ext_vector_type(8)));
typedef __bf16 bf16x2 __attribute__((ext_vector_type(2)));
typedef float  f32x16 __attribute__((ext_vector_type(16)));
typedef unsigned int u32x4 __attribute__((ext_vector_type(4)));

#define NB   2
#define SEQ  2048
#define NHQ  32
#define NHKV 8
#define HD   128
#define KVSTR 1024                 // floats between consecutive kv rows
#define NTILE 32                   // kv tiles of 64 per (b,hkv)
#define TILE_ELEMS 8192            // 64*128 bf16
#define TILE_BYTES 16384
#define SCL2E 0.12753599963140488f // (1/sqrt(128)) * log2(e)

static __device__ inline unsigned pk2(float a, float b) {
    bf16x2 t = {(__bf16)a, (__bf16)b};
    return __builtin_bit_cast(unsigned, t);
}

static __device__ inline void gload16(const void* g, void* l) {
    __builtin_amdgcn_global_load_lds(
        (const __attribute__((address_space(1))) unsigned*)g,
        (__attribute__((address_space(3))) unsigned*)l, 16, 0, 0);
}

// ---- prep: fp32 K,V -> bf16 pre-swizzled K' (row-major) / V' (transposed) --
// K' elem: blk*8192 + row*128 + (d ^ ((row&15)<<3))
// V' elem: blk*8192 + d*64 + (kv ^ (((d>>2)&7)<<3))      blk = (b*8+hkv)*32+t
__global__ __launch_bounds__(256) void prep_kv(
    const float* __restrict__ kg, const float* __restrict__ vg,
    __bf16* __restrict__ kws, __bf16* __restrict__ vws)
{
    __shared__ float vt[TILE_ELEMS];
    const int blk = blockIdx.x;
    const int tid = threadIdx.x;
    const int t   = blk & 31;
    const int bh  = blk >> 5;
    const int hkv = bh & 7;
    const int b   = bh >> 3;
    const float* ks = kg + (((size_t)b * SEQ + t * 64) * NHKV + hkv) * HD;
    const float* vs = vg + (((size_t)b * SEQ + t * 64) * NHKV + hkv) * HD;
    __bf16* kd = kws + (size_t)blk * TILE_ELEMS;
    __bf16* vd = vws + (size_t)blk * TILE_ELEMS;

    // K: thread handles row = tid>>2, 32 d's starting at (tid&3)*32
    {
        const int row = tid >> 2, ds0 = (tid & 3) * 32;
        const float* kr = ks + (size_t)row * KVSTR + ds0;
        const int X = (row & 15) << 3;
#pragma unroll
        for (int gI = 0; gI < 4; ++gI) {
            const float4 a = *(const float4*)(kr + gI * 8);
            const float4 c = *(const float4*)(kr + gI * 8 + 4);
            bf16x8 o = {(__bf16)a.x, (__bf16)a.y, (__bf16)a.z, (__bf16)a.w,
                        (__bf16)c.x, (__bf16)c.y, (__bf16)c.z, (__bf16)c.w};
            *(bf16x8*)&kd[row * 128 + ((ds0 + gI * 8) ^ X)] = o;
        }
    }
    // V: stage fp32 tile to LDS (coalesced), emit transposed + kv-XOR
#pragma unroll
    for (int i = 0; i < 8; ++i) {
        const int e = (tid + i * 256) * 4;
        *(float4*)&vt[e] = *(const float4*)(vs + (size_t)(e >> 7) * KVSTR + (e & 127));
    }
    __syncthreads();
    {
        const int d = tid >> 1, kv0 = (tid & 1) * 32;
        const int Xd = ((d >> 2) & 7) << 3;
#pragma unroll
        for (int gI = 0; gI < 4; ++gI) {
            const int kv8 = kv0 + gI * 8;
            bf16x8 o;
#pragma unroll
            for (int j = 0; j < 8; ++j) o[j] = (__bf16)vt[(kv8 + j) * 128 + d];
            *(bf16x8*)&vd[d * 64 + (kv8 ^ Xd)] = o;
        }
    }
}

// ---- main: R4 structure, DMA staging from pre-swizzled KV' -----------------
__global__ __launch_bounds__(512, 2) void gqa_attn_fwd(
    const float* __restrict__ qg, const __bf16* __restrict__ kws,
    const __bf16* __restrict__ vws, float* __restrict__ og)
{
    __shared__ __align__(16) __bf16 Kl[2][TILE_ELEMS];
    __shared__ __align__(16) __bf16 Vt[2][TILE_ELEMS];

    const int tid  = threadIdx.x;
    const int w    = tid >> 6;
    const int lane = tid & 63;
    const int l31  = lane & 31;
    const int hi   = lane >> 5;

    // R4 mapping (measured best): blocks c and c+256 complementary
    const int bid = blockIdx.x;
    const int qt  = (bid < 256) ? (7 - (bid >> 6)) : ((bid - 256) >> 6);
    const int sub = bid & 63;
    const int hq  = sub & 31;
    const int b   = sub >> 5;
    const int qb  = qt * 256;
    const int hkv = hq >> 2;

    const int ntiles = qt * 4 + 4;
    const int Tw     = qt * 4 + (w >> 1) + 1;    // this wave's active tiles

    // ---- Q fragments: lane owns q-row qb+32w+l31; B-frag k = 8*hi + j ------
    const int qrow = qb + w * 32 + l31;
    const float* qp = qg + (((size_t)b * SEQ + qrow) * NHQ + hq) * HD;
    bf16x8 bq[8];
#pragma unroll
    for (int s = 0; s < 8; ++s) {
        const int d0 = s * 16 + hi * 8;
        const float4 f0 = *(const float4*)(qp + d0);
        const float4 f1 = *(const float4*)(qp + d0 + 4);
        bf16x8 t = {(__bf16)f0.x, (__bf16)f0.y, (__bf16)f0.z, (__bf16)f0.w,
                    (__bf16)f1.x, (__bf16)f1.y, (__bf16)f1.z, (__bf16)f1.w};
        bq[s] = t;
    }

    // ---- DMA staging: 4 x global_load_lds(16B) per thread per tile ---------
    const char* kpb = (const char*)(kws + (size_t)((b * 8 + hkv) * NTILE) * TILE_ELEMS);
    const char* vpb = (const char*)(vws + (size_t)((b * 8 + hkv) * NTILE) * TILE_ELEMS);
    const int soff = w * 2048 + (lane << 4);   // per-lane source offset
    const int doff = w * 2048;                 // wave-uniform LDS offset

    auto stage = [&](int t, int buf) {
        const char* ksrc = kpb + (size_t)t * TILE_BYTES;
        const char* vsrc = vpb + (size_t)t * TILE_BYTES;
#pragma unroll
        for (int r = 0; r < 2; ++r)
            gload16(ksrc + soff + r * 1024, (char*)&Kl[buf][0] + doff + r * 1024);
#pragma unroll
        for (int r = 0; r < 2; ++r)
            gload16(vsrc + soff + r * 1024, (char*)&Vt[buf][0] + doff + r * 1024);
    };

    f32x16 acc[4] = {};       // acc[db]: O[q=crow(r,hi)][d=db*32+l31]
    float m_r = -1e30f, l_r = 0.f;   // scaled-log2 domain

    const int swk = (l31 & 15) << 3;   // K read swizzle (lane-constant)
    const int swv = (l31 >> 2) << 3;   // V read swizzle (lane-constant)

    stage(0, 0);                        // prologue

    for (int t = 0; t < ntiles; ++t) {
        const int cur = t & 1;
        // my 4 outstanding loads are exactly tile t's
        asm volatile("s_waitcnt vmcnt(0)" ::: "memory");
        __builtin_amdgcn_s_barrier();   // all waves: tile t landed; t-1 reads done
        __builtin_amdgcn_sched_barrier(0);
        if (t + 1 < ntiles) stage(t + 1, cur ^ 1);   // lands under this compute

        const bool active = (t < Tw);
        if (active) {
            // ---- swapped QK^T: S^T[kv][q], A=K, B=Q ------------------------
            f32x16 sf[2];
            __builtin_amdgcn_s_setprio(1);
#pragma unroll
            for (int kb = 0; kb < 2; ++kb) {
                sf[kb] = (f32x16)(0.f);
                const int krow = kb * 32 + l31;
#pragma unroll
                for (int s = 0; s < 8; ++s) {
                    const int d0 = s * 16 + hi * 8;
                    const bf16x8 ak = *(const bf16x8*)&Kl[cur][krow * 128 + (d0 ^ swk)];
                    sf[kb] = __builtin_amdgcn_mfma_f32_32x32x16_bf16(ak, bq[s], sf[kb], 0, 0, 0);
                }
            }
            __builtin_amdgcn_s_setprio(0);

            // ---- mask (raw domain), max tree, defer-rescale ----------------
            if (t == Tw - 1) {
#pragma unroll
                for (int kb = 0; kb < 2; ++kb)
#pragma unroll
                    for (int r = 0; r < 16; ++r) {
                        const int kvg = t * 64 + kb * 32 + ((r & 3) + ((r >> 2) << 3) + (hi << 2));
                        if (kvg > qrow) sf[kb][r] = -1e30f;
                    }
            }
            float t16[16];
#pragma unroll
            for (int r = 0; r < 16; ++r) t16[r] = fmaxf(sf[0][r], sf[1][r]);
#pragma unroll
            for (int r = 0; r < 8; ++r) t16[r] = fmaxf(t16[r], t16[r + 8]);
#pragma unroll
            for (int r = 0; r < 4; ++r) t16[r] = fmaxf(t16[r], t16[r + 4]);
            float pm = fmaxf(fmaxf(t16[0], t16[1]), fmaxf(t16[2], t16[3]));
            pm = fmaxf(pm, __shfl_xor(pm, 32));
            const float pms = pm * SCL2E;

            if (__any(pms - m_r > 8.0f)) {            // T13
                const float mn = fmaxf(m_r, pms);
                const float alpha = exp2f(m_r - mn);
                m_r = mn;
                l_r *= alpha;
#pragma unroll
                for (int r = 0; r < 16; ++r) {
                    const float ab = __shfl(alpha, (r & 3) + ((r >> 2) << 3) + (hi << 2));
#pragma unroll
                    for (int db = 0; db < 4; ++db) acc[db][r] *= ab;
                }
            }

            // ---- exp (scale folded into fma) + row sum ---------------------
            float p[2][16];
#pragma unroll
            for (int kb = 0; kb < 2; ++kb)
#pragma unroll
                for (int r = 0; r < 16; ++r)
                    p[kb][r] = exp2f(fmaf(sf[kb][r], SCL2E, -m_r));
            {
                float s16[16];
#pragma unroll
                for (int r = 0; r < 16; ++r) s16[r] = p[0][r] + p[1][r];
#pragma unroll
                for (int r = 0; r < 8; ++r) s16[r] += s16[r + 8];
#pragma unroll
                for (int r = 0; r < 4; ++r) s16[r] += s16[r + 4];
                float rs = (s16[0] + s16[1]) + (s16[2] + s16[3]);
                rs += __shfl_xor(rs, 32);
                l_r += rs;
            }

            // ---- T12: P -> bf16 A-frags via pack + permlane32_swap ---------
            bf16x8 pa[4];
#pragma unroll
            for (int ks2 = 0; ks2 < 4; ++ks2) {
                const int kb = ks2 >> 1, c = (ks2 & 1) * 8;
                unsigned x0 = pk2(p[kb][c + 0], p[kb][c + 1]);
                unsigned x1 = pk2(p[kb][c + 2], p[kb][c + 3]);
                unsigned y0 = pk2(p[kb][c + 4], p[kb][c + 5]);
                unsigned y1 = pk2(p[kb][c + 6], p[kb][c + 7]);
                asm volatile("v_permlane32_swap_b32 %0, %1" : "+v"(x0), "+v"(y0));
                asm volatile("v_permlane32_swap_b32 %0, %1" : "+v"(x1), "+v"(y1));
                u32x4 u = {x0, x1, y0, y1};
                pa[ks2] = __builtin_bit_cast(bf16x8, u);
            }

            // ---- PV: acc[db] += P(32q x 16kv) * V(16kv x 32d) --------------
            __builtin_amdgcn_s_setprio(1);
#pragma unroll
            for (int db = 0; db < 4; ++db) {
                const int dbase = (db * 32 + l31) * 64;
#pragma unroll
                for (int ks2 = 0; ks2 < 4; ++ks2) {
                    const int kvo = ks2 * 16 + hi * 8;
                    const bf16x8 bv = *(const bf16x8*)&Vt[cur][dbase + (kvo ^ swv)];
                    acc[db] = __builtin_amdgcn_mfma_f32_32x32x16_bf16(pa[ks2], bv, acc[db], 0, 0, 0);
                }
            }
            __builtin_amdgcn_s_setprio(0);
        }
    }

    // ---- epilogue: out = acc / l -------------------------------------------
    const float linv = 1.0f / l_r;
#pragma unroll
    for (int r = 0; r < 16; ++r) {
        const int crow = (r & 3) + ((r >> 2) << 3) + (hi << 2);
        const float lb = __shfl(linv, crow);
        const int qg_row = qb + w * 32 + crow;
        float* op = og + (((size_t)b * SEQ + qg_row) * NHQ + hq) * HD + l31;
#pragma unroll
        for (int db = 0; db < 4; ++db) op[db * 32] = acc[db][r] * lb;
    }
}

extern "C" void kernel_launch(void* const* d_in, const int* in_sizes, int n_in,
                              void* d_out, int out_size, void* d_ws, size_t ws_size,
                              hipStream_t stream) {
    const float* q = (const float*)d_in[0];
    const float* k = (const float*)d_in[1];
    const float* v = (const float*)d_in[2];
    float* out = (float*)d_out;
    __bf16* kws = (__bf16*)d_ws;
    __bf16* vws = kws + (size_t)NB * NHKV * NTILE * TILE_ELEMS;  // +8.39 MB

    prep_kv<<<dim3(NB * NHKV * NTILE), dim3(256), 0, stream>>>(k, v, kws, vws);
    gqa_attn_fwd<<<dim3((SEQ / 256) * NHQ * NB), dim3(512), 0, stream>>>(q, kws, vws, out);
}